// Round 1
// baseline (63.452 us; speedup 1.0000x reference)
//
#include <hip/hip_runtime.h>

// Shapes are static per the reference: sequence (64, 512, 2048) fp32.
constexpr int B = 64;
constexpr int S = 512;
constexpr int F = 2048;
constexpr int F4 = F / 4;          // 512 float4 columns
constexpr int NPAIR = S - 1;       // 511 consecutive pairs
constexpr int TSEG = 16;           // t-segments (for occupancy)
constexpr int PAIRS_PER_SEG = 32;  // ceil(511/16)

// loss = 0.2 * dot(mult, pair_mse) / count
//   mult[t] = (t==0 || t==510) ? 1 : 2
//   pair_mse[t] = (1/(B*F)) * sum_{b,f} diff^2
//   count = (S-W+1)*(W-1) = 510*2 = 1020
constexpr double SCALE_D = 0.2 / (1020.0 * (double)(B) * (double)(F));

__global__ __launch_bounds__(256)
void TemporalConsistencyLoss_kernel(const float4* __restrict__ seq,
                                    float* __restrict__ out) {
    // block decomposition: fb (f-half) | seg (t-segment) | b (batch)
    const int fb  = blockIdx.x & 1;
    const int seg = (blockIdx.x >> 1) & (TSEG - 1);
    const int b   = blockIdx.x >> 5;

    const int f4 = fb * 256 + threadIdx.x;            // float4 column
    const int t0 = seg * PAIRS_PER_SEG;               // first pair index
    const int t1 = (t0 + PAIRS_PER_SEG < NPAIR) ? t0 + PAIRS_PER_SEG : NPAIR;

    const float4* p = seq + (size_t)b * S * F4 + (size_t)t0 * F4 + f4;
    float4 prev = *p;
    p += F4;

    float acc = 0.0f;
#pragma unroll 4
    for (int t = t0; t < t1; ++t) {
        float4 cur = *p;
        p += F4;
        float dx = cur.x - prev.x;
        float dy = cur.y - prev.y;
        float dz = cur.z - prev.z;
        float dw = cur.w - prev.w;
        float s2 = dx * dx + dy * dy + dz * dz + dw * dw;
        float w  = (t == 0 || t == NPAIR - 1) ? 1.0f : 2.0f;
        acc = fmaf(w, s2, acc);
        prev = cur;
    }

    // wave (64-lane) shuffle reduction
    for (int off = 32; off > 0; off >>= 1)
        acc += __shfl_down(acc, off, 64);

    __shared__ float wave_sums[4];
    const int lane = threadIdx.x & 63;
    const int wv   = threadIdx.x >> 6;
    if (lane == 0) wave_sums[wv] = acc;
    __syncthreads();

    if (threadIdx.x == 0) {
        float s = wave_sums[0] + wave_sums[1] + wave_sums[2] + wave_sums[3];
        atomicAdd(out, s * (float)SCALE_D);
    }
}

extern "C" void kernel_launch(void* const* d_in, const int* in_sizes, int n_in,
                              void* d_out, int out_size, void* d_ws, size_t ws_size,
                              hipStream_t stream) {
    const float4* seq = (const float4*)d_in[0];
    float* out = (float*)d_out;

    // d_out is not re-poisoned/zeroed between timed replays; atomicAdd needs 0.
    hipMemsetAsync(out, 0, sizeof(float), stream);

    const int grid = B * TSEG * 2;  // 2048 blocks
    TemporalConsistencyLoss_kernel<<<grid, 256, 0, stream>>>(seq, out);
}

// Round 2
// 45.298 us; speedup vs baseline: 1.4008x; 1.4008x over previous
//
#include <hip/hip_runtime.h>

// Shapes are static per the reference: sequence (64, 512, 2048) fp32.
constexpr int B = 64;
constexpr int S = 512;
constexpr int F = 2048;
constexpr int F4 = F / 4;          // 512 float4 columns
constexpr int NPAIR = S - 1;       // 511 consecutive pairs
constexpr int TSEG = 16;           // t-segments (for occupancy)
constexpr int PAIRS_PER_SEG = 32;  // ceil(511/16)
constexpr int GRID = B * TSEG * 2; // 2048 blocks

// loss = 0.2 * dot(mult, pair_mse) / count
//   mult[t] = (t==0 || t==510) ? 1 : 2
//   pair_mse[t] = (1/(B*F)) * sum_{b,f} diff^2
//   count = (S-W+1)*(W-1) = 510*2 = 1020
constexpr double SCALE_D = 0.2 / (1020.0 * (double)(B) * (double)(F));

__global__ __launch_bounds__(256)
void tcl_partial_kernel(const float4* __restrict__ seq,
                        float* __restrict__ partials) {
    // block decomposition: fb (f-half) | seg (t-segment) | b (batch)
    const int fb  = blockIdx.x & 1;
    const int seg = (blockIdx.x >> 1) & (TSEG - 1);
    const int b   = blockIdx.x >> 5;

    const int f4 = fb * 256 + threadIdx.x;            // float4 column
    const int t0 = seg * PAIRS_PER_SEG;               // first pair index
    const int t1 = (t0 + PAIRS_PER_SEG < NPAIR) ? t0 + PAIRS_PER_SEG : NPAIR;

    const float4* p = seq + (size_t)b * S * F4 + (size_t)t0 * F4 + f4;
    float4 prev = *p;
    p += F4;

    float acc = 0.0f;
#pragma unroll 8
    for (int t = t0; t < t1; ++t) {
        float4 cur = *p;
        p += F4;
        float dx = cur.x - prev.x;
        float dy = cur.y - prev.y;
        float dz = cur.z - prev.z;
        float dw = cur.w - prev.w;
        float s2 = dx * dx + dy * dy + dz * dz + dw * dw;
        float w  = (t == 0 || t == NPAIR - 1) ? 1.0f : 2.0f;
        acc = fmaf(w, s2, acc);
        prev = cur;
    }

    // wave (64-lane) shuffle reduction
    for (int off = 32; off > 0; off >>= 1)
        acc += __shfl_down(acc, off, 64);

    __shared__ float wave_sums[4];
    const int lane = threadIdx.x & 63;
    const int wv   = threadIdx.x >> 6;
    if (lane == 0) wave_sums[wv] = acc;
    __syncthreads();

    if (threadIdx.x == 0) {
        partials[blockIdx.x] =
            wave_sums[0] + wave_sums[1] + wave_sums[2] + wave_sums[3];
    }
}

__global__ __launch_bounds__(256)
void tcl_reduce_kernel(const float* __restrict__ partials,
                       float* __restrict__ out) {
    float acc = 0.0f;
#pragma unroll
    for (int i = 0; i < GRID / 256; ++i)
        acc += partials[threadIdx.x + i * 256];

    for (int off = 32; off > 0; off >>= 1)
        acc += __shfl_down(acc, off, 64);

    __shared__ float wave_sums[4];
    const int lane = threadIdx.x & 63;
    const int wv   = threadIdx.x >> 6;
    if (lane == 0) wave_sums[wv] = acc;
    __syncthreads();

    if (threadIdx.x == 0) {
        float s = wave_sums[0] + wave_sums[1] + wave_sums[2] + wave_sums[3];
        out[0] = s * (float)SCALE_D;
    }
}

extern "C" void kernel_launch(void* const* d_in, const int* in_sizes, int n_in,
                              void* d_out, int out_size, void* d_ws, size_t ws_size,
                              hipStream_t stream) {
    const float4* seq = (const float4*)d_in[0];
    float* partials = (float*)d_ws;   // 2048 floats, plain stores (no zeroing needed)
    float* out = (float*)d_out;

    tcl_partial_kernel<<<GRID, 256, 0, stream>>>(seq, partials);
    tcl_reduce_kernel<<<1, 256, 0, stream>>>(partials, out);
}